// Round 6
// baseline (235.965 us; speedup 1.0000x reference)
//
#include <hip/hip_runtime.h>
#include <cstdint>
#include <cstddef>

// ---------------------------------------------------------------------------
// MHA forward, bf16 MFMA pipeline.
// B=2, S=2048, D=1024, H=16, dk=64.
//   1) prep:   cast q,k,v,W* fp32->bf16; mask -> additive float (log2 domain)
//   2) proj3:  128x128 tiles, 768-block grid = exactly 3 blocks/CU
//   3) attn:   R10 core: rb=4 (64 q-rows/wave, 256/block), grid 256 = 1
//              block/CU -- K/V fragment reads amortized over 4 rb. P->PV via
//              the R0-PROVEN per-wave LDS round-trip (NO inline-asm permlane;
//              diagnostic isolation of the R7/R9 corruption). R6-proven body:
//              stage-first/barrier-last, triple-buffered K/V, mask dbuf.
//   4) oproj:  64x128 tiles (2 blocks/CU), out = ao@Wo^T + bo (fp32)
// ---------------------------------------------------------------------------

using bf16   = __bf16;
using bf16x4 = __attribute__((ext_vector_type(4))) __bf16;
using bf16x8 = __attribute__((ext_vector_type(8))) __bf16;
using f32x4  = __attribute__((ext_vector_type(4))) float;

#define MFMA_BF16(a, b, c) __builtin_amdgcn_mfma_f32_16x16x32_bf16((a), (b), (c), 0, 0, 0)

__device__ __forceinline__ void gload_lds16(const void* g, void* l) {
  __builtin_amdgcn_global_load_lds((__attribute__((address_space(1))) void*)g,
                                   (__attribute__((address_space(3))) void*)l,
                                   16, 0, 0);
}

#define LOG2E 1.4426950408889634f

// ---------------------------------------------------------------------------
// 1) prep
// ---------------------------------------------------------------------------
__global__ __launch_bounds__(256) void prep_kernel(
    const float* __restrict__ q, const float* __restrict__ k, const float* __restrict__ v,
    const int* __restrict__ mask,
    const float* __restrict__ Wq, const float* __restrict__ Wk,
    const float* __restrict__ Wv, const float* __restrict__ Wo,
    bf16* __restrict__ qb, bf16* __restrict__ kb, bf16* __restrict__ vb,
    bf16* __restrict__ Wqb, bf16* __restrict__ Wkb, bf16* __restrict__ Wvb,
    bf16* __restrict__ Wob, float* __restrict__ maskf)
{
  const int NQ = 1048576;
  const int NW = 262144;
  int i = blockIdx.x * 256 + threadIdx.x;
  if (i < 3 * NQ) {
    const float* src; bf16* dst; int j;
    if (i < NQ)        { src = q; dst = qb; j = i; }
    else if (i < 2*NQ) { src = k; dst = kb; j = i - NQ; }
    else               { src = v; dst = vb; j = i - 2*NQ; }
    float4 f = ((const float4*)src)[j];
    ((bf16x4*)dst)[j] = bf16x4{(bf16)f.x, (bf16)f.y, (bf16)f.z, (bf16)f.w};
  } else if (i < 3*NQ + 4*NW) {
    int j = i - 3*NQ;
    const float* src; bf16* dst;
    if (j < NW)        { src = Wq; dst = Wqb; }
    else if (j < 2*NW) { src = Wk; dst = Wkb; j -= NW; }
    else if (j < 3*NW) { src = Wv; dst = Wvb; j -= 2*NW; }
    else               { src = Wo; dst = Wob; j -= 3*NW; }
    float4 f = ((const float4*)src)[j];
    ((bf16x4*)dst)[j] = bf16x4{(bf16)f.x, (bf16)f.y, (bf16)f.z, (bf16)f.w};
  } else if (i < 3*NQ + 4*NW + 1024) {
    int j = i - 3*NQ - 4*NW;
    int4 mi = ((const int4*)mask)[j];
    float4 o;
    o.x = (mi.x == 0) ? -1e9f * LOG2E : 0.0f;
    o.y = (mi.y == 0) ? -1e9f * LOG2E : 0.0f;
    o.z = (mi.z == 0) ? -1e9f * LOG2E : 0.0f;
    o.w = (mi.w == 0) ? -1e9f * LOG2E : 0.0f;
    ((float4*)maskf)[j] = o;
  }
}

// ---------------------------------------------------------------------------
// 2) fused QKV projections, 128x128 tiles, grid 768 = 3 blocks/CU exactly.
// ---------------------------------------------------------------------------
__global__ __launch_bounds__(256, 3) void proj3_kernel(
    const bf16* __restrict__ Xq, const bf16* __restrict__ Xk, const bf16* __restrict__ Xv,
    const bf16* __restrict__ Wqb, const bf16* __restrict__ Wkb, const bf16* __restrict__ Wvb,
    const float* __restrict__ bq, const float* __restrict__ bk, const float* __restrict__ bv,
    bf16* __restrict__ qh, bf16* __restrict__ kh, bf16* __restrict__ vhT)
{
  __shared__ bf16 As[128 * 64];   // 16 KB
  __shared__ bf16 Bs[128 * 64];   // 16 KB

  const int bid = blockIdx.x;
  const int z   = bid >> 8;        // 0,1,2
  const int r_  = bid & 255;

  const int tid = threadIdx.x, w = tid >> 6, lane = tid & 63;
  const int wr = w >> 1, wc = w & 1;
  const int quad = lane >> 4, l16 = lane & 15;
  const int sw = l16 & 7;
  const int srow8 = lane >> 3;
  const int scol  = ((lane & 7) ^ srow8) * 8;

  const bf16* Aptr; const bf16* Bptr;
  int m0, n0;
  if (z == 2) { Aptr = Wvb; Bptr = Xv; m0 = (r_ >> 5) * 128; n0 = (r_ & 31) * 128; }
  else        { Aptr = (z == 0) ? Xq : Xk; Bptr = (z == 0) ? Wqb : Wkb;
                m0 = (r_ >> 3) * 128; n0 = (r_ & 7) * 128; }

  f32x4 acc[4][4];
#pragma unroll
  for (int mt = 0; mt < 4; ++mt)
#pragma unroll
    for (int nt = 0; nt < 4; ++nt)
      acc[mt][nt] = f32x4{0.f, 0.f, 0.f, 0.f};

  for (int k0 = 0; k0 < 1024; k0 += 64) {
#pragma unroll
    for (int c8 = 0; c8 < 8; ++c8) {
      const int c = w * 8 + c8;
      if (c < 16) {
        const int row = c * 8 + srow8;
        gload_lds16(Aptr + (size_t)(m0 + row) * 1024 + k0 + scol, As + c * 512);
      } else {
        const int cB = c - 16;
        const int row = cB * 8 + srow8;
        gload_lds16(Bptr + (size_t)(n0 + row) * 1024 + k0 + scol, Bs + cB * 512);
      }
    }
    __syncthreads();
#pragma unroll
    for (int kk = 0; kk < 2; ++kk) {
      bf16x8 af[4], bf[4];
#pragma unroll
      for (int mt = 0; mt < 4; ++mt)
        af[mt] = *(const bf16x8*)(As + (wr*64 + mt*16 + l16) * 64 + ((kk*4 + quad) ^ sw) * 8);
#pragma unroll
      for (int nt = 0; nt < 4; ++nt)
        bf[nt] = *(const bf16x8*)(Bs + (wc*64 + nt*16 + l16) * 64 + ((kk*4 + quad) ^ sw) * 8);
#pragma unroll
      for (int mt = 0; mt < 4; ++mt)
#pragma unroll
        for (int nt = 0; nt < 4; ++nt)
          acc[mt][nt] = MFMA_BF16(af[mt], bf[nt], acc[mt][nt]);
    }
    __syncthreads();
  }

  if (z == 2) {
#pragma unroll
    for (int mt = 0; mt < 4; ++mt) {
      const int dvb = m0 + wr*64 + mt*16 + quad*4;
      const float4 bv4 = *(const float4*)(bv + dvb);
#pragma unroll
      for (int nt = 0; nt < 4; ++nt) {
        const int tok = n0 + wc*64 + nt*16 + l16;
        const int bb = tok >> 11, s = tok & 2047;
#pragma unroll
        for (int r = 0; r < 4; ++r) {
          const int dv = dvb + r;
          const int h = dv >> 6, d = dv & 63;
          vhT[(((size_t)bb*16 + h)*64 + d)*2048 + s] = (bf16)(acc[mt][nt][r] + (&bv4.x)[r]);
        }
      }
    }
  } else {
    const float* bias = (z == 0) ? bq : bk;
#pragma unroll
    for (int mt = 0; mt < 4; ++mt) {
#pragma unroll
      for (int nt = 0; nt < 4; ++nt) {
        const int n = n0 + wc*64 + nt*16 + l16;
        const int h = n >> 6, d = n & 63;
        const float bn = bias[n];
#pragma unroll
        for (int r = 0; r < 4; ++r) {
          const int m  = m0 + wr*64 + mt*16 + quad*4 + r;
          const int bb = m >> 11, s = m & 2047;
          const float val = acc[mt][nt][r] + bn;
          if (z == 0)
            qh[(((size_t)bb*16 + h)*2048 + s)*64 + d] = (bf16)(val * (0.125f * LOG2E));
          else
            kh[(((size_t)bb*16 + h)*2048 + s)*64 + d] = (bf16)val;
        }
      }
    }
  }
}

// ---------------------------------------------------------------------------
// 3) flash attention (R10 core): 256-thr blocks (4 waves), rb=4 -> 64 q-rows
// per wave, 256 per block; grid 256 = 1 block/CU. K/V fragments read ONCE per
// wave per tile, amortized over 4 rb (halves LDS bytes per q-row vs rb=2).
// P->PV via per-wave LDS round-trip (R0-proven path; no inline-asm permlane).
// R6-proven body order: stage(t+2) first, mask(t+1) prefetch, fK/fV reads,
// rb loop, ONE __syncthreads at end (full drain; stage has 1-body flight).
// L -> (bh,qt): bh=(L&7)+8*(L>>6) (XCD pinning), qt=(L>>3)&7. Bijective.
// ---------------------------------------------------------------------------
#define PSTRIDE 72   // P staging row stride (64+8): banks rotate, 16B aligned

__global__ __launch_bounds__(256, 1) void attn_kernel(
    const bf16* __restrict__ qh, const bf16* __restrict__ kh,
    const bf16* __restrict__ vhT, const float* __restrict__ maskf,
    bf16* __restrict__ out)
{
  __shared__ bf16 KV[3][2][4096];       // [buf][K|V][64*64], 48 KB, XOR-swz
  __shared__ bf16 Ps[4][16 * PSTRIDE];  // per-wave P staging, 9 KB

  const int tid = threadIdx.x, w = tid >> 6, lane = tid & 63;
  const int quad = lane >> 4, l16 = lane & 15;
  const int sw = l16 & 7;
  const int srow8 = lane >> 3;
  const int scol  = ((lane & 7) ^ srow8) * 8;

  const int L  = blockIdx.x;
  const int bh = (L & 7) + ((L >> 6) << 3);   // xcd-pinned head group
  const int qt = (L >> 3) & 7;                // 8 q-tiles of 256 rows
  const int b  = bh >> 4, h = bh & 15;
  const int q0 = qt * 256 + w * 64;

  const bf16* kbase = kh  + (size_t)bh * 2048 * 64;
  const bf16* vbase = vhT + (size_t)bh * 64 * 2048;
  const bf16* qbase = qh  + ((size_t)bh * 2048 + q0) * 64;
  const float* mbase = maskf + (size_t)b * 2048 + quad * 4;

  char* kvb = (char*)&KV[0][0][0];
  bf16* Pw = Ps[w];

  auto stageTo = [&](int t, int bufoff) {
    const int kt0 = t * 64;
#pragma unroll
    for (int c2 = 0; c2 < 2; ++c2) {
      const int c   = w * 2 + c2;        // chunk 0..7, 1KB each
      const int row = c * 8 + srow8;
      gload_lds16(kbase + (size_t)(kt0 + row) * 64 + scol, kvb + bufoff + c * 1024);
      gload_lds16(vbase + (size_t)row * 2048 + kt0 + scol, kvb + bufoff + 8192 + c * 1024);
    }
  };

  // Q fragments (B-operand for S^T = K.Q^T): 4 rb blocks of 16 q-rows
  bf16x8 aQ[4][2];
#pragma unroll
  for (int rb = 0; rb < 4; ++rb)
#pragma unroll
    for (int kk = 0; kk < 2; ++kk)
      aQ[rb][kk] = *(const bf16x8*)(qbase + (size_t)(rb*16 + l16)*64 + kk*32 + quad*8);

  // loop-invariant LDS addressing
  const int laneA = l16 * 128 + ((quad    ) ^ sw) * 16;   // kk=0 slot
  const int laneB = l16 * 128 + ((quad + 4) ^ sw) * 16;   // kk=1 slot
  bf16*       bW = Pw + l16 * PSTRIDE + quad * 4;
  const bf16* bR = Pw + l16 * PSTRIDE + quad * 8;

  f32x4 Oacc[4][4];            // O^T: row d = mb*16+quad*4+r, col q = l16
  f32x4 lacc[4];               // vectorized softmax denominator partials
#pragma unroll
  for (int rb = 0; rb < 4; ++rb) {
    lacc[rb] = f32x4{0.f, 0.f, 0.f, 0.f};
#pragma unroll
    for (int mb = 0; mb < 4; ++mb) Oacc[rb][mb] = f32x4{0.f, 0.f, 0.f, 0.f};
  }

  // prologue: stage tiles 0 and 1, load mask tile 0, publish
  stageTo(0, 0);
  stageTo(1, 16384);
  float4 mk[4], mkn[4];
#pragma unroll
  for (int mb = 0; mb < 4; ++mb) mk[mb] = *(const float4*)(mbase + mb*16);
  __syncthreads();

  int kvcur = 0, kvnxt = 16384, kvnn = 32768;

  for (int t = 0; t < 32; ++t) {
    if (t < 30) stageTo(t + 2, kvnn);
    if (t < 31) {
#pragma unroll
      for (int mb = 0; mb < 4; ++mb)
        mkn[mb] = *(const float4*)(mbase + (t + 1)*64 + mb*16);
    }

    // fragment reads for tile t (staged 2 tiles ago, drained at t-2's barrier)
    bf16x8 fK[8], fV[8];
    {
      const char* pA = kvb + kvcur + laneA;
      const char* pB = kvb + kvcur + laneB;
#pragma unroll
      for (int mb = 0; mb < 4; ++mb) {
        fK[mb*2+0] = *(const bf16x8*)(pA + mb*2048);
        fK[mb*2+1] = *(const bf16x8*)(pB + mb*2048);
      }
      pA += 8192; pB += 8192;
#pragma unroll
      for (int mb = 0; mb < 4; ++mb) {
        fV[mb*2+0] = *(const bf16x8*)(pA + mb*2048);
        fV[mb*2+1] = *(const bf16x8*)(pB + mb*2048);
      }
    }

#pragma unroll
    for (int rb = 0; rb < 4; ++rb) {
      // S^T tile, C-initialized with the additive mask (free masking)
      f32x4 sac[4];
#pragma unroll
      for (int mb = 0; mb < 4; ++mb)
        sac[mb] = f32x4{mk[mb].x, mk[mb].y, mk[mb].z, mk[mb].w};
#pragma unroll
      for (int kk = 0; kk < 2; ++kk)
#pragma unroll
        for (int mb = 0; mb < 4; ++mb)
          sac[mb] = MFMA_BF16(fK[mb*2+kk], aQ[rb][kk], sac[mb]);

      // direct exp2 (no max subtraction), accumulate l per-lane
      float p[4][4];
#pragma unroll
      for (int mb = 0; mb < 4; ++mb) {
#pragma unroll
        for (int r = 0; r < 4; ++r) p[mb][r] = __builtin_amdgcn_exp2f(sac[mb][r]);
        lacc[rb] += f32x4{p[mb][0], p[mb][1], p[mb][2], p[mb][3]};
      }

      // P round-trip (C-layout -> B-operand), wave-private, in-order DS ops
#pragma unroll
      for (int mb = 0; mb < 4; ++mb) {
        bf16x4 pk = bf16x4{(bf16)p[mb][0], (bf16)p[mb][1], (bf16)p[mb][2], (bf16)p[mb][3]};
        *(bf16x4*)(bW + mb*16) = pk;
      }
#pragma unroll
      for (int kk = 0; kk < 2; ++kk) {
        bf16x8 aP = *(const bf16x8*)(bR + kk*32);
#pragma unroll
        for (int mb = 0; mb < 4; ++mb)
          Oacc[rb][mb] = MFMA_BF16(fV[mb*2+kk], aP, Oacc[rb][mb]);
      }
    }

#pragma unroll
    for (int mb = 0; mb < 4; ++mb) mk[mb] = mkn[mb];

    __syncthreads();
    int tmp_ = kvcur; kvcur = kvnxt; kvnxt = kvnn; kvnn = tmp_;
  }

  // final l reduction across quads (once), then normalize + store O^T
#pragma unroll
  for (int rb = 0; rb < 4; ++rb) {
    float l_ = lacc[rb][0] + lacc[rb][1] + lacc[rb][2] + lacc[rb][3];
    l_ += __shfl_xor(l_, 16);
    l_ += __shfl_xor(l_, 32);
    const float inv = 1.0f / l_;
#pragma unroll
    for (int mb = 0; mb < 4; ++mb) {
      bf16x4 o = bf16x4{(bf16)(Oacc[rb][mb][0]*inv), (bf16)(Oacc[rb][mb][1]*inv),
                        (bf16)(Oacc[rb][mb][2]*inv), (bf16)(Oacc[rb][mb][3]*inv)};
      *(bf16x4*)(out + ((size_t)b*2048 + q0 + rb*16 + l16)*1024 + h*64 + mb*16 + quad*4) = o;
    }
  }
}

// ---------------------------------------------------------------------------
// 4) output projection: 64x128 tiles, grid (64,8) = 512 blocks = 2/CU.
// ---------------------------------------------------------------------------
__global__ __launch_bounds__(256) void oproj_kernel(
    const bf16* __restrict__ Ain, const bf16* __restrict__ Wob,
    const float* __restrict__ bo, float* __restrict__ out)
{
  __shared__ bf16 As[64 * 64];     // 8 KB
  __shared__ bf16 Bs[128 * 64];    // 16 KB
  const int m0 = blockIdx.x * 64, n0 = blockIdx.y * 128;

  const int tid = threadIdx.x, w = tid >> 6, lane = tid & 63;
  const int quad = lane >> 4, l16 = lane & 15;
  const int sw = l16 & 7;
  const int srow8 = lane >> 3;
  const int scol  = ((lane & 7) ^ srow8) * 8;

  f32x4 acc[4][2];
#pragma unroll
  for (int mt = 0; mt < 4; ++mt)
#pragma unroll
    for (int nt = 0; nt < 2; ++nt)
      acc[mt][nt] = f32x4{0.f, 0.f, 0.f, 0.f};

  for (int k0 = 0; k0 < 1024; k0 += 64) {
#pragma unroll
    for (int c4 = 0; c4 < 6; ++c4) {
      const int c = w * 6 + c4;
      if (c < 8) {
        const int row = c * 8 + srow8;
        gload_lds16(Ain + (size_t)(m0 + row) * 1024 + k0 + scol, As + c * 512);
      } else {
        const int cB = c - 8;
        const int row = cB * 8 + srow8;
        gload_lds16(Wob + (size_t)(n0 + row) * 1024 + k0 + scol, Bs + cB * 512);
      }
    }
    __syncthreads();
#pragma unroll
    for (int kk = 0; kk < 2; ++kk) {
      bf16x8 af[4], bfr[2];
#pragma unroll
      for (int mt = 0; mt < 4; ++mt)
        af[mt] = *(const bf16x8*)(As + (mt*16 + l16) * 64 + ((kk*4 + quad) ^ sw) * 8);
#pragma unroll
      for (int nt = 0; nt < 2; ++nt)
        bfr[nt] = *(const bf16x8*)(Bs + (w*32 + nt*16 + l16) * 64 + ((kk*4 + quad) ^ sw) * 8);
#pragma unroll
      for (int mt = 0; mt < 4; ++mt)
#pragma unroll
        for (int nt = 0; nt < 2; ++nt)
          acc[mt][nt] = MFMA_BF16(af[mt], bfr[nt], acc[mt][nt]);
    }
    __syncthreads();
  }

#pragma unroll
  for (int mt = 0; mt < 4; ++mt) {
#pragma unroll
    for (int nt = 0; nt < 2; ++nt) {
      const int n = n0 + w*32 + nt*16 + l16;
      const float bn = bo[n];
#pragma unroll
      for (int r = 0; r < 4; ++r) {
        const int m = m0 + mt*16 + quad*4 + r;
        out[(size_t)m * 1024 + n] = acc[mt][nt][r] + bn;
      }
    }
  }
}

// ---------------------------------------------------------------------------
extern "C" void kernel_launch(void* const* d_in, const int* in_sizes, int n_in,
                              void* d_out, int out_size, void* d_ws, size_t ws_size,
                              hipStream_t stream)
{
  const float* q    = (const float*)d_in[0];
  const float* k    = (const float*)d_in[1];
  const float* v    = (const float*)d_in[2];
  const int*   mask = (const int*)d_in[3];
  const float* Wq   = (const float*)d_in[4];
  const float* bq   = (const float*)d_in[5];
  const float* Wk   = (const float*)d_in[6];
  const float* bk   = (const float*)d_in[7];
  const float* Wv   = (const float*)d_in[8];
  const float* bv   = (const float*)d_in[9];
  const float* Wo   = (const float*)d_in[10];
  const float* bo   = (const float*)d_in[11];

  char* ws = (char*)d_ws;
  bf16*  qb    = (bf16*)(ws);
  bf16*  kb    = (bf16*)(ws + (8ull  << 20));
  bf16*  vb    = (bf16*)(ws + (16ull << 20));
  bf16*  Wqb   = (bf16*)(ws + (24ull << 20));
  bf16*  Wkb   = (bf16*)(ws + (26ull << 20));
  bf16*  Wvb   = (bf16*)(ws + (28ull << 20));
  bf16*  Wob   = (bf16*)(ws + (30ull << 20));
  float* maskf = (float*)(ws + (32ull << 20));
  bf16*  qh    = (bf16*)(ws + (33ull << 20));
  bf16*  kh    = (bf16*)(ws + (41ull << 20));
  bf16*  vhT   = (bf16*)(ws + (49ull << 20));
  bf16*  ao    = (bf16*)(ws);                    // reuse qb region
  float* out   = (float*)d_out;

  prep_kernel<<<16388, 256, 0, stream>>>(q, k, v, mask, Wq, Wk, Wv, Wo,
                                         qb, kb, vb, Wqb, Wkb, Wvb, Wob, maskf);
  proj3_kernel<<<768, 256, 0, stream>>>(qb, kb, vb, Wqb, Wkb, Wvb,
                                        bq, bk, bv, qh, kh, vhT);
  attn_kernel<<<256, 256, 0, stream>>>(qh, kh, vhT, maskf, ao);
  oproj_kernel<<<dim3(64, 8), 256, 0, stream>>>(ao, Wob, bo, out);
}

// Round 7
// 213.681 us; speedup vs baseline: 1.1043x; 1.1043x over previous
//
#include <hip/hip_runtime.h>
#include <cstdint>
#include <cstddef>

// ---------------------------------------------------------------------------
// MHA forward, bf16 MFMA pipeline.
// B=2, S=2048, D=1024, H=16, dk=64.
//   1) prep:   cast q,k,v,W* fp32->bf16; mask -> additive float (log2 domain);
//              2-element grid-stride (8194 blocks)
//   2) proj3:  128x128 tiles, 768-block grid = exactly 3 blocks/CU
//   3) attn:   R6 core (proven): rb=2, grid 512 = 2 blocks/CU, triple-buffered
//              K/V LDS, K-fragments register-prefetched one tile ahead,
//              in-register P->PV via cvt_pk + permlane32/16_swap (safe at
//              VGPR~116; corrupts only under rb=4 pressure), 1 barrier/tile.
//   4) oproj:  64x128 tiles (2 blocks/CU), out = ao@Wo^T + bo (fp32)
// ---------------------------------------------------------------------------

using bf16   = __bf16;
using bf16x4 = __attribute__((ext_vector_type(4))) __bf16;
using bf16x8 = __attribute__((ext_vector_type(8))) __bf16;
using f32x4  = __attribute__((ext_vector_type(4))) float;

#define MFMA_BF16(a, b, c) __builtin_amdgcn_mfma_f32_16x16x32_bf16((a), (b), (c), 0, 0, 0)

__device__ __forceinline__ void gload_lds16(const void* g, void* l) {
  __builtin_amdgcn_global_load_lds((__attribute__((address_space(1))) void*)g,
                                   (__attribute__((address_space(3))) void*)l,
                                   16, 0, 0);
}

// pack 2 f32 -> 1 dword of 2 bf16 (src0 -> low half)
#define CVT_PK(d, lo, hi) \
  asm("v_cvt_pk_bf16_f32 %0, %1, %2" : "=v"(d) : "v"(lo), "v"(hi))
// x' = (x_q0,x_q1,y_q0,y_q1), y' = (x_q2,x_q3,y_q2,y_q3)
#define SWAP32(x, y) \
  asm("v_permlane32_swap_b32 %0, %1" : "+v"(x), "+v"(y))
// x' = (x_q0,y_q0,x_q2,y_q2), y' = (x_q1,y_q1,x_q3,y_q3)
#define SWAP16(x, y) \
  asm("v_permlane16_swap_b32 %0, %1" : "+v"(x), "+v"(y))

#define LOG2E 1.4426950408889634f

// ---------------------------------------------------------------------------
// 1) prep — 2 elements per thread, grid 8194
// ---------------------------------------------------------------------------
__global__ __launch_bounds__(256) void prep_kernel(
    const float* __restrict__ q, const float* __restrict__ k, const float* __restrict__ v,
    const int* __restrict__ mask,
    const float* __restrict__ Wq, const float* __restrict__ Wk,
    const float* __restrict__ Wv, const float* __restrict__ Wo,
    bf16* __restrict__ qb, bf16* __restrict__ kb, bf16* __restrict__ vb,
    bf16* __restrict__ Wqb, bf16* __restrict__ Wkb, bf16* __restrict__ Wvb,
    bf16* __restrict__ Wob, float* __restrict__ maskf)
{
  const int NQ = 1048576;
  const int NW = 262144;
  const int STRIDE = 8194 * 256;
#pragma unroll
  for (int s = 0; s < 2; ++s) {
    int i = blockIdx.x * 256 + threadIdx.x + s * STRIDE;
    if (i < 3 * NQ) {
      const float* src; bf16* dst; int j;
      if (i < NQ)        { src = q; dst = qb; j = i; }
      else if (i < 2*NQ) { src = k; dst = kb; j = i - NQ; }
      else               { src = v; dst = vb; j = i - 2*NQ; }
      float4 f = ((const float4*)src)[j];
      ((bf16x4*)dst)[j] = bf16x4{(bf16)f.x, (bf16)f.y, (bf16)f.z, (bf16)f.w};
    } else if (i < 3*NQ + 4*NW) {
      int j = i - 3*NQ;
      const float* src; bf16* dst;
      if (j < NW)        { src = Wq; dst = Wqb; }
      else if (j < 2*NW) { src = Wk; dst = Wkb; j -= NW; }
      else if (j < 3*NW) { src = Wv; dst = Wvb; j -= 2*NW; }
      else               { src = Wo; dst = Wob; j -= 3*NW; }
      float4 f = ((const float4*)src)[j];
      ((bf16x4*)dst)[j] = bf16x4{(bf16)f.x, (bf16)f.y, (bf16)f.z, (bf16)f.w};
    } else if (i < 3*NQ + 4*NW + 1024) {
      int j = i - 3*NQ - 4*NW;
      int4 mi = ((const int4*)mask)[j];
      float4 o;
      o.x = (mi.x == 0) ? -1e9f * LOG2E : 0.0f;
      o.y = (mi.y == 0) ? -1e9f * LOG2E : 0.0f;
      o.z = (mi.z == 0) ? -1e9f * LOG2E : 0.0f;
      o.w = (mi.w == 0) ? -1e9f * LOG2E : 0.0f;
      ((float4*)maskf)[j] = o;
    }
  }
}

// ---------------------------------------------------------------------------
// 2) fused QKV projections, 128x128 tiles, grid 768 = 3 blocks/CU exactly.
// ---------------------------------------------------------------------------
__global__ __launch_bounds__(256, 3) void proj3_kernel(
    const bf16* __restrict__ Xq, const bf16* __restrict__ Xk, const bf16* __restrict__ Xv,
    const bf16* __restrict__ Wqb, const bf16* __restrict__ Wkb, const bf16* __restrict__ Wvb,
    const float* __restrict__ bq, const float* __restrict__ bk, const float* __restrict__ bv,
    bf16* __restrict__ qh, bf16* __restrict__ kh, bf16* __restrict__ vhT)
{
  __shared__ bf16 As[128 * 64];   // 16 KB
  __shared__ bf16 Bs[128 * 64];   // 16 KB

  const int bid = blockIdx.x;
  const int z   = bid >> 8;        // 0,1,2
  const int r_  = bid & 255;

  const int tid = threadIdx.x, w = tid >> 6, lane = tid & 63;
  const int wr = w >> 1, wc = w & 1;
  const int quad = lane >> 4, l16 = lane & 15;
  const int sw = l16 & 7;
  const int srow8 = lane >> 3;
  const int scol  = ((lane & 7) ^ srow8) * 8;

  const bf16* Aptr; const bf16* Bptr;
  int m0, n0;
  if (z == 2) { Aptr = Wvb; Bptr = Xv; m0 = (r_ >> 5) * 128; n0 = (r_ & 31) * 128; }
  else        { Aptr = (z == 0) ? Xq : Xk; Bptr = (z == 0) ? Wqb : Wkb;
                m0 = (r_ >> 3) * 128; n0 = (r_ & 7) * 128; }

  f32x4 acc[4][4];
#pragma unroll
  for (int mt = 0; mt < 4; ++mt)
#pragma unroll
    for (int nt = 0; nt < 4; ++nt)
      acc[mt][nt] = f32x4{0.f, 0.f, 0.f, 0.f};

  for (int k0 = 0; k0 < 1024; k0 += 64) {
#pragma unroll
    for (int c8 = 0; c8 < 8; ++c8) {
      const int c = w * 8 + c8;
      if (c < 16) {
        const int row = c * 8 + srow8;
        gload_lds16(Aptr + (size_t)(m0 + row) * 1024 + k0 + scol, As + c * 512);
      } else {
        const int cB = c - 16;
        const int row = cB * 8 + srow8;
        gload_lds16(Bptr + (size_t)(n0 + row) * 1024 + k0 + scol, Bs + cB * 512);
      }
    }
    __syncthreads();
#pragma unroll
    for (int kk = 0; kk < 2; ++kk) {
      bf16x8 af[4], bf[4];
#pragma unroll
      for (int mt = 0; mt < 4; ++mt)
        af[mt] = *(const bf16x8*)(As + (wr*64 + mt*16 + l16) * 64 + ((kk*4 + quad) ^ sw) * 8);
#pragma unroll
      for (int nt = 0; nt < 4; ++nt)
        bf[nt] = *(const bf16x8*)(Bs + (wc*64 + nt*16 + l16) * 64 + ((kk*4 + quad) ^ sw) * 8);
#pragma unroll
      for (int mt = 0; mt < 4; ++mt)
#pragma unroll
        for (int nt = 0; nt < 4; ++nt)
          acc[mt][nt] = MFMA_BF16(af[mt], bf[nt], acc[mt][nt]);
    }
    __syncthreads();
  }

  if (z == 2) {
#pragma unroll
    for (int mt = 0; mt < 4; ++mt) {
      const int dvb = m0 + wr*64 + mt*16 + quad*4;
      const float4 bv4 = *(const float4*)(bv + dvb);
#pragma unroll
      for (int nt = 0; nt < 4; ++nt) {
        const int tok = n0 + wc*64 + nt*16 + l16;
        const int bb = tok >> 11, s = tok & 2047;
#pragma unroll
        for (int r = 0; r < 4; ++r) {
          const int dv = dvb + r;
          const int h = dv >> 6, d = dv & 63;
          vhT[(((size_t)bb*16 + h)*64 + d)*2048 + s] = (bf16)(acc[mt][nt][r] + (&bv4.x)[r]);
        }
      }
    }
  } else {
    const float* bias = (z == 0) ? bq : bk;
#pragma unroll
    for (int mt = 0; mt < 4; ++mt) {
#pragma unroll
      for (int nt = 0; nt < 4; ++nt) {
        const int n = n0 + wc*64 + nt*16 + l16;
        const int h = n >> 6, d = n & 63;
        const float bn = bias[n];
#pragma unroll
        for (int r = 0; r < 4; ++r) {
          const int m  = m0 + wr*64 + mt*16 + quad*4 + r;
          const int bb = m >> 11, s = m & 2047;
          const float val = acc[mt][nt][r] + bn;
          if (z == 0)
            qh[(((size_t)bb*16 + h)*2048 + s)*64 + d] = (bf16)(val * (0.125f * LOG2E));
          else
            kh[(((size_t)bb*16 + h)*2048 + s)*64 + d] = (bf16)val;
        }
      }
    }
  }
}

// ---------------------------------------------------------------------------
// 3) flash attention (R6 core, proven): 256-thr blocks (4 waves, 128 q-rows),
// grid 512 = 2 blocks/CU; triple-buffered K/V LDS; K-fragments register-
// prefetched one tile ahead; P C-layout -> PV B-operand redistribution fully
// in-register (cvt_pk + permlane32/16 swaps). 1 barrier/tile.
// bh=(L&7)+8*(L>>7) XCD pinning.
// ---------------------------------------------------------------------------

#define ATTN_BODY(T, FKC, FKN, MKC, MKN)                                        \
  {                                                                             \
    if ((T) < 30) stageTo((T) + 2, kvnn);                                       \
    if ((T) < 31) {                                                             \
      _Pragma("unroll")                                                         \
      for (int mb = 0; mb < 4; ++mb)                                            \
        MKN[mb] = *(const float4*)(mbase + ((T) + 1) * 64 + mb * 16);           \
      const char* pA = kvb + kvnxt + laneA;                                     \
      const char* pB = kvb + kvnxt + laneB;                                     \
      _Pragma("unroll")                                                         \
      for (int mb = 0; mb < 4; ++mb) {                                          \
        FKN[mb*2+0] = *(const bf16x8*)(pA + mb*2048);                           \
        FKN[mb*2+1] = *(const bf16x8*)(pB + mb*2048);                           \
      }                                                                         \
    }                                                                           \
    bf16x8 fV[8];                                                               \
    {                                                                           \
      const char* pA = kvb + kvcur + 8192 + laneA;                              \
      const char* pB = kvb + kvcur + 8192 + laneB;                              \
      _Pragma("unroll")                                                         \
      for (int mb = 0; mb < 4; ++mb) {                                          \
        fV[mb*2+0] = *(const bf16x8*)(pA + mb*2048);                            \
        fV[mb*2+1] = *(const bf16x8*)(pB + mb*2048);                            \
      }                                                                         \
    }                                                                           \
    _Pragma("unroll")                                                           \
    for (int rb = 0; rb < 2; ++rb) {                                            \
      f32x4 sac[4];                                                             \
      _Pragma("unroll")                                                         \
      for (int mb = 0; mb < 4; ++mb)                                            \
        sac[mb] = f32x4{MKC[mb].x, MKC[mb].y, MKC[mb].z, MKC[mb].w};            \
      _Pragma("unroll")                                                         \
      for (int kk = 0; kk < 2; ++kk)                                            \
        _Pragma("unroll")                                                       \
        for (int mb = 0; mb < 4; ++mb)                                          \
          sac[mb] = MFMA_BF16(FKC[mb*2+kk], aQ[rb][kk], sac[mb]);               \
      float p[4][4];                                                            \
      _Pragma("unroll")                                                         \
      for (int mb = 0; mb < 4; ++mb) {                                          \
        _Pragma("unroll")                                                       \
        for (int r = 0; r < 4; ++r) p[mb][r] = __builtin_amdgcn_exp2f(sac[mb][r]); \
        lacc[rb] += f32x4{p[mb][0], p[mb][1], p[mb][2], p[mb][3]};              \
      }                                                                         \
      uint32_t pk0[4], pk1[4];                                                  \
      _Pragma("unroll")                                                         \
      for (int mb = 0; mb < 4; ++mb) {                                          \
        CVT_PK(pk0[mb], p[mb][0], p[mb][1]);                                    \
        CVT_PK(pk1[mb], p[mb][2], p[mb][3]);                                    \
      }                                                                         \
      _Pragma("unroll")                                                         \
      for (int kk = 0; kk < 2; ++kk) {                                          \
        uint32_t a0 = pk0[2*kk], b0 = pk0[2*kk+1];                              \
        uint32_t a1 = pk1[2*kk], b1 = pk1[2*kk+1];                              \
        SWAP32(a0, b0); SWAP16(a0, b0);                                         \
        SWAP32(a1, b1); SWAP16(a1, b1);                                         \
        union { uint32_t u[4]; bf16x8 v; } un;                                  \
        un.u[0] = a0; un.u[1] = a1; un.u[2] = b0; un.u[3] = b1;                 \
        _Pragma("unroll")                                                       \
        for (int mb = 0; mb < 4; ++mb)                                          \
          Oacc[rb][mb] = MFMA_BF16(fV[mb*2+kk], un.v, Oacc[rb][mb]);            \
      }                                                                         \
    }                                                                           \
    __syncthreads();                                                            \
    { int tmp_ = kvcur; kvcur = kvnxt; kvnxt = kvnn; kvnn = tmp_; }             \
  }

__global__ __launch_bounds__(256, 2) void attn_kernel(
    const bf16* __restrict__ qh, const bf16* __restrict__ kh,
    const bf16* __restrict__ vhT, const float* __restrict__ maskf,
    bf16* __restrict__ out)
{
  __shared__ bf16 KV[3][2][4096];         // [buf][K|V][64*64], 48 KB, XOR-swz

  const int tid = threadIdx.x, w = tid >> 6, lane = tid & 63;
  const int quad = lane >> 4, l16 = lane & 15;
  const int sw = l16 & 7;
  const int srow8 = lane >> 3;
  const int scol  = ((lane & 7) ^ srow8) * 8;

  const int L  = blockIdx.x;
  const int bh = (L & 7) + ((L >> 7) << 3);
  const int qt = (L >> 3) & 15;
  const int b  = bh >> 4, h = bh & 15;
  const int q0 = qt * 128 + w * 32;

  const bf16* kbase = kh  + (size_t)bh * 2048 * 64;
  const bf16* vbase = vhT + (size_t)bh * 64 * 2048;
  const bf16* qbase = qh  + ((size_t)bh * 2048 + q0) * 64;
  const float* mbase = maskf + (size_t)b * 2048 + quad * 4;

  char* kvb = (char*)&KV[0][0][0];

  // stage tile t into buffer at byte offset bufoff: K 8 chunks + V 8 chunks,
  // 4 waves x (2+2). LDS dest is wave-uniform base (HW adds lane*16); the
  // XOR swizzle is baked into the per-lane GLOBAL source address.
  auto stageTo = [&](int t, int bufoff) {
    const int kt0 = t * 64;
#pragma unroll
    for (int c2 = 0; c2 < 2; ++c2) {
      const int c   = w * 2 + c2;        // chunk 0..7, 1KB each
      const int row = c * 8 + srow8;
      gload_lds16(kbase + (size_t)(kt0 + row) * 64 + scol, kvb + bufoff + c * 1024);
      gload_lds16(vbase + (size_t)row * 2048 + kt0 + scol, kvb + bufoff + 8192 + c * 1024);
    }
  };

  // Q fragments (B-operand for S^T = K.Q^T)
  bf16x8 aQ[2][2];
#pragma unroll
  for (int rb = 0; rb < 2; ++rb)
#pragma unroll
    for (int kk = 0; kk < 2; ++kk)
      aQ[rb][kk] = *(const bf16x8*)(qbase + (size_t)(rb*16 + l16)*64 + kk*32 + quad*8);

  // loop-invariant LDS addressing (all ds ops get immediate offsets)
  const int laneA = l16 * 128 + ((quad    ) ^ sw) * 16;   // kk=0 slot
  const int laneB = l16 * 128 + ((quad + 4) ^ sw) * 16;   // kk=1 slot

  f32x4 Oacc[2][4];            // O^T: row d = mb*16+quad*4+r, col q = l16
  f32x4 lacc[2];               // vectorized softmax denominator partials
#pragma unroll
  for (int rb = 0; rb < 2; ++rb) {
    lacc[rb] = f32x4{0.f, 0.f, 0.f, 0.f};
#pragma unroll
    for (int mb = 0; mb < 4; ++mb) Oacc[rb][mb] = f32x4{0.f, 0.f, 0.f, 0.f};
  }

  // prologue: stage tiles 0 and 1, load mask tile 0, publish, prefetch fK(0)
  stageTo(0, 0);
  stageTo(1, 16384);
  float4 mkA[4], mkB[4];
#pragma unroll
  for (int mb = 0; mb < 4; ++mb) mkA[mb] = *(const float4*)(mbase + mb*16);
  __syncthreads();

  bf16x8 fKa[8], fKb[8];
  {
    const char* pA = kvb + laneA;
    const char* pB = kvb + laneB;
#pragma unroll
    for (int mb = 0; mb < 4; ++mb) {
      fKa[mb*2+0] = *(const bf16x8*)(pA + mb*2048);
      fKa[mb*2+1] = *(const bf16x8*)(pB + mb*2048);
    }
  }

  int kvcur = 0, kvnxt = 16384, kvnn = 32768;

  for (int tt = 0; tt < 32; tt += 2) {
    ATTN_BODY(tt,     fKa, fKb, mkA, mkB);
    ATTN_BODY(tt + 1, fKb, fKa, mkB, mkA);
  }

  // final l reduction across quads (once), then normalize + store O^T
#pragma unroll
  for (int rb = 0; rb < 2; ++rb) {
    float l_ = lacc[rb][0] + lacc[rb][1] + lacc[rb][2] + lacc[rb][3];
    l_ += __shfl_xor(l_, 16);
    l_ += __shfl_xor(l_, 32);
    const float inv = 1.0f / l_;
#pragma unroll
    for (int mb = 0; mb < 4; ++mb) {
      bf16x4 o = bf16x4{(bf16)(Oacc[rb][mb][0]*inv), (bf16)(Oacc[rb][mb][1]*inv),
                        (bf16)(Oacc[rb][mb][2]*inv), (bf16)(Oacc[rb][mb][3]*inv)};
      *(bf16x4*)(out + ((size_t)b*2048 + q0 + rb*16 + l16)*1024 + h*64 + mb*16 + quad*4) = o;
    }
  }
}

// ---------------------------------------------------------------------------
// 4) output projection: 64x128 tiles, grid (64,8) = 512 blocks = 2/CU.
// ---------------------------------------------------------------------------
__global__ __launch_bounds__(256) void oproj_kernel(
    const bf16* __restrict__ Ain, const bf16* __restrict__ Wob,
    const float* __restrict__ bo, float* __restrict__ out)
{
  __shared__ bf16 As[64 * 64];     // 8 KB
  __shared__ bf16 Bs[128 * 64];    // 16 KB
  const int m0 = blockIdx.x * 64, n0 = blockIdx.y * 128;

  const int tid = threadIdx.x, w = tid >> 6, lane = tid & 63;
  const int quad = lane >> 4, l16 = lane & 15;
  const int sw = l16 & 7;
  const int srow8 = lane >> 3;
  const int scol  = ((lane & 7) ^ srow8) * 8;

  f32x4 acc[4][2];
#pragma unroll
  for (int mt = 0; mt < 4; ++mt)
#pragma unroll
    for (int nt = 0; nt < 2; ++nt)
      acc[mt][nt] = f32x4{0.f, 0.f, 0.f, 0.f};

  for (int k0 = 0; k0 < 1024; k0 += 64) {
#pragma unroll
    for (int c4 = 0; c4 < 6; ++c4) {
      const int c = w * 6 + c4;
      if (c < 8) {
        const int row = c * 8 + srow8;
        gload_lds16(Ain + (size_t)(m0 + row) * 1024 + k0 + scol, As + c * 512);
      } else {
        const int cB = c - 8;
        const int row = cB * 8 + srow8;
        gload_lds16(Wob + (size_t)(n0 + row) * 1024 + k0 + scol, Bs + cB * 512);
      }
    }
    __syncthreads();
#pragma unroll
    for (int kk = 0; kk < 2; ++kk) {
      bf16x8 af[4], bfr[2];
#pragma unroll
      for (int mt = 0; mt < 4; ++mt)
        af[mt] = *(const bf16x8*)(As + (mt*16 + l16) * 64 + ((kk*4 + quad) ^ sw) * 8);
#pragma unroll
      for (int nt = 0; nt < 2; ++nt)
        bfr[nt] = *(const bf16x8*)(Bs + (w*32 + nt*16 + l16) * 64 + ((kk*4 + quad) ^ sw) * 8);
#pragma unroll
      for (int mt = 0; mt < 4; ++mt)
#pragma unroll
        for (int nt = 0; nt < 2; ++nt)
          acc[mt][nt] = MFMA_BF16(af[mt], bfr[nt], acc[mt][nt]);
    }
    __syncthreads();
  }

#pragma unroll
  for (int mt = 0; mt < 4; ++mt) {
#pragma unroll
    for (int nt = 0; nt < 2; ++nt) {
      const int n = n0 + w*32 + nt*16 + l16;
      const float bn = bo[n];
#pragma unroll
      for (int r = 0; r < 4; ++r) {
        const int m = m0 + mt*16 + quad*4 + r;
        out[(size_t)m * 1024 + n] = acc[mt][nt][r] + bn;
      }
    }
  }
}

// ---------------------------------------------------------------------------
extern "C" void kernel_launch(void* const* d_in, const int* in_sizes, int n_in,
                              void* d_out, int out_size, void* d_ws, size_t ws_size,
                              hipStream_t stream)
{
  const float* q    = (const float*)d_in[0];
  const float* k    = (const float*)d_in[1];
  const float* v    = (const float*)d_in[2];
  const int*   mask = (const int*)d_in[3];
  const float* Wq   = (const float*)d_in[4];
  const float* bq   = (const float*)d_in[5];
  const float* Wk   = (const float*)d_in[6];
  const float* bk   = (const float*)d_in[7];
  const float* Wv   = (const float*)d_in[8];
  const float* bv   = (const float*)d_in[9];
  const float* Wo   = (const float*)d_in[10];
  const float* bo   = (const float*)d_in[11];

  char* ws = (char*)d_ws;
  bf16*  qb    = (bf16*)(ws);
  bf16*  kb    = (bf16*)(ws + (8ull  << 20));
  bf16*  vb    = (bf16*)(ws + (16ull << 20));
  bf16*  Wqb   = (bf16*)(ws + (24ull << 20));
  bf16*  Wkb   = (bf16*)(ws + (26ull << 20));
  bf16*  Wvb   = (bf16*)(ws + (28ull << 20));
  bf16*  Wob   = (bf16*)(ws + (30ull << 20));
  float* maskf = (float*)(ws + (32ull << 20));
  bf16*  qh    = (bf16*)(ws + (33ull << 20));
  bf16*  kh    = (bf16*)(ws + (41ull << 20));
  bf16*  vhT   = (bf16*)(ws + (49ull << 20));
  bf16*  ao    = (bf16*)(ws);                    // reuse qb region
  float* out   = (float*)d_out;

  prep_kernel<<<8194, 256, 0, stream>>>(q, k, v, mask, Wq, Wk, Wv, Wo,
                                        qb, kb, vb, Wqb, Wkb, Wvb, Wob, maskf);
  proj3_kernel<<<768, 256, 0, stream>>>(qb, kb, vb, Wqb, Wkb, Wvb,
                                        bq, bk, bv, qh, kh, vhT);
  attn_kernel<<<512, 256, 0, stream>>>(qh, kh, vhT, maskf, ao);
  oproj_kernel<<<dim3(64, 8), 256, 0, stream>>>(ao, Wob, bo, out);
}